// Round 1
// baseline (53.428 us; speedup 1.0000x reference)
//
#include <hip/hip_runtime.h>

// DarcySolver: batched constant-tridiagonal solve via closed-form Green's
// function + block-level prefix scan.
//
// Reference math (N=512, B=128, k=0.1):
//   h = 1/511, c = k/h = 51.1
//   u[b,0]   = 0                     (identity row, f=sin(0))
//   u[b,511] = sin(float32(pi))      (identity row)  ~= -8.742278e-8
//   interior (m=510 unknowns, 1-based j=1..510):
//     T x = g,  T = tridiag(-1,2,-1),  g_j = forcing[b,j] * h/(2c) = forcing * h^2/(2k)
//   T^-1[k][j] = min(k,j)*(511-max(k,j))/511  (exact)
//   => x_k = ((511-k)*S1_k + k*S2_k)/511,
//      S1_k = sum_{j<=k} j*g_j   (prefix),  S2_k = sum_{j>k} (511-j)*g_j (suffix = total - prefix)

#define NN   512
#define BATCH 128

__global__ __launch_bounds__(NN) void darcy_solve_kernel(
    const float* __restrict__ forcing, float* __restrict__ out) {
    __shared__ float sA[NN];  // prefix of j*g_j
    __shared__ float sC[NN];  // prefix of (511-j)*g_j

    const int b = blockIdx.x;
    const int t = threadIdx.x;

    // h^2 / (2*k) = (1/511)^2 / 0.2
    const float scale = (float)((1.0 / 511.0) * (1.0 / 511.0) / 0.2);

    const float fval = forcing[b * NN + t];
    const float g = (t >= 1 && t <= NN - 2) ? fval * scale : 0.0f;

    sA[t] = (float)t * g;
    sC[t] = (float)(NN - 1 - t) * g;
    __syncthreads();

    // Inclusive Hillis-Steele scan over both arrays (9 doubling steps).
    #pragma unroll
    for (int off = 1; off < NN; off <<= 1) {
        float va = 0.0f, vc = 0.0f;
        if (t >= off) { va = sA[t - off]; vc = sC[t - off]; }
        __syncthreads();
        sA[t] += va;
        sC[t] += vc;
        __syncthreads();
    }

    const float ctot = sC[NN - 1];

    float u;
    if (t == 0) {
        u = 0.0f;                       // sin(0)
    } else if (t == NN - 1) {
        u = -8.7422777e-08f;            // sin(float32(pi)) in fp32
    } else {
        const float s1 = sA[t];               // sum_{j<=t} j*g_j
        const float s2 = ctot - sC[t];        // sum_{j>t} (511-j)*g_j
        u = ((float)(NN - 1 - t) * s1 + (float)t * s2) * (1.0f / 511.0f);
    }
    out[b * NN + t] = u;
}

extern "C" void kernel_launch(void* const* d_in, const int* in_sizes, int n_in,
                              void* d_out, int out_size, void* d_ws, size_t ws_size,
                              hipStream_t stream) {
    const float* forcing = (const float*)d_in[0];
    float* out = (float*)d_out;
    darcy_solve_kernel<<<dim3(BATCH), dim3(NN), 0, stream>>>(forcing, out);
}

// Round 2
// 52.643 us; speedup vs baseline: 1.0149x; 1.0149x over previous
//
#include <hip/hip_runtime.h>

// DarcySolver: batched constant-tridiagonal solve via closed-form Green's
// function. R2: one wave per batch row, register-only scan (no LDS, no
// __syncthreads) — 8 elems/lane serial prefix + 6-step __shfl_up wave scan.
//
// Math (N=512, B=128, k=0.1):
//   u[b,0] = 0;  u[b,511] = sin(float32(pi)) ~= -8.742278e-8
//   interior: T x = g, T = tridiag(-1,2,-1), g_j = forcing[b,j]*h^2/(2k)
//   T^-1[k][j] = min(k,j)*(511-max(k,j))/511
//   x_k = ((511-k)*S1_k + k*S2_k)/511,
//     S1_k = prefix of j*g_j, S2_k = suffix of (511-j)*g_j = total - prefix.

#define NN    512
#define BATCH 128

__global__ __launch_bounds__(64) void darcy_wave_kernel(
    const float* __restrict__ forcing, float* __restrict__ out) {
    const int b    = blockIdx.x;
    const int lane = threadIdx.x;       // 0..63, one full wave
    const int base = lane * 8;          // 8 consecutive elements per lane

    // h^2 / (2*k) = (1/511)^2 / 0.2
    const float scale = (float)((1.0 / 511.0) * (1.0 / 511.0) / 0.2);

    // 32 B/lane coalesced load (wave covers the full 2 KB row)
    const float4* fp = (const float4*)(forcing + b * NN + base);
    const float4 f0 = fp[0];
    const float4 f1 = fp[1];
    const float f[8] = {f0.x, f0.y, f0.z, f0.w, f1.x, f1.y, f1.z, f1.w};

    // Per-lane serial inclusive prefix of a_j = j*g_j and c_j = (511-j)*g_j
    float pa[8], pc[8];
    float ra = 0.0f, rc = 0.0f;
#pragma unroll
    for (int i = 0; i < 8; ++i) {
        const int j = base + i;
        const float g = (j >= 1 && j <= NN - 2) ? f[i] * scale : 0.0f;
        ra += (float)j * g;
        rc += (float)(NN - 1 - j) * g;
        pa[i] = ra;
        pc[i] = rc;
    }

    // Wave-level inclusive scan of lane totals (ra, rc) — 6 doubling steps.
    float sa = ra, sc = rc;
#pragma unroll
    for (int off = 1; off < 64; off <<= 1) {
        const float ua = __shfl_up(sa, off, 64);
        const float uc = __shfl_up(sc, off, 64);
        if (lane >= off) { sa += ua; sc += uc; }
    }
    const float offA = sa - ra;           // exclusive prefix for this lane
    const float offC = sc - rc;
    const float ctot = __shfl(sc, 63, 64);  // total of all c_j

    float o[8];
#pragma unroll
    for (int i = 0; i < 8; ++i) {
        const int j  = base + i;
        const float PA = offA + pa[i];          // sum_{m<=j} a_m
        const float PC = offC + pc[i];          // sum_{m<=j} c_m
        o[i] = ((float)(NN - 1 - j) * PA + (float)j * (ctot - PC)) * (1.0f / 511.0f);
    }
    if (lane == 0)  o[0] = 0.0f;            // sin(0)
    if (lane == 63) o[7] = -8.7422777e-08f; // sin(float32(pi))

    float4* op = (float4*)(out + b * NN + base);
    op[0] = make_float4(o[0], o[1], o[2], o[3]);
    op[1] = make_float4(o[4], o[5], o[6], o[7]);
}

extern "C" void kernel_launch(void* const* d_in, const int* in_sizes, int n_in,
                              void* d_out, int out_size, void* d_ws, size_t ws_size,
                              hipStream_t stream) {
    const float* forcing = (const float*)d_in[0];
    float* out = (float*)d_out;
    darcy_wave_kernel<<<dim3(BATCH), dim3(64), 0, stream>>>(forcing, out);
}